// Round 5
// baseline (3259.995 us; speedup 1.0000x reference)
//
#include <hip/hip_runtime.h>
#include <hip/hip_bf16.h>
#include <cstddef>

#define T_STEPS 512
#define ROWS    65536      // B*T = 128*512
#define XW      544        // full feature width

typedef __attribute__((ext_vector_type(8))) short bf16x8;
typedef __attribute__((ext_vector_type(4))) float f32x4;

__device__ __forceinline__ float fast_sigmoid(float x) {
    return 1.f / (1.f + __expf(-x));
}
__device__ __forceinline__ float fast_tanh(float x) {
    x = fminf(fmaxf(x, -15.f), 15.f);
    float e = __expf(2.f * x);
    return (e - 1.f) / (e + 1.f);
}

// ---------------------------------------------------------------------------
// Weight prep: fp32 -> bf16, layout [Npad][Kpad] row-major, zero padded.
// mode dc>0: conv weight src [N][dc][2] -> dst[n][k] = k<dc ? w[n][k][0] : w[n][k-dc][1]
// ---------------------------------------------------------------------------
struct WDesc { const float* src; int N; int Npad; int K; int Kpad; int dc; long long off; };
struct WTab  { WDesc e[14]; };

__global__ __launch_bounds__(256) void prep_weights(WTab tab, __hip_bfloat16* __restrict__ dst) {
    WDesc d = tab.e[blockIdx.x];
    const int total = d.Npad * d.Kpad;
    for (int idx = blockIdx.y * blockDim.x + threadIdx.x; idx < total;
         idx += gridDim.y * blockDim.x) {
        int n = idx / d.Kpad;
        int k = idx - n * d.Kpad;
        float v = 0.f;
        if (n < d.N && k < d.K) {
            if (d.dc > 0)
                v = (k < d.dc) ? d.src[(n * d.dc + k) * 2]
                               : d.src[(n * d.dc + (k - d.dc)) * 2 + 1];
            else
                v = d.src[(size_t)n * d.K + k];
        }
        dst[d.off + idx] = __float2bfloat16(v);
    }
}

// features [ROWS][40] fp32 -> fbf [ROWS][64] bf16 (zero padded)
__global__ __launch_bounds__(256) void prep_features(const float* __restrict__ f,
                                                     __hip_bfloat16* __restrict__ o) {
    for (int idx = blockIdx.x * blockDim.x + threadIdx.x; idx < ROWS * 64;
         idx += gridDim.x * blockDim.x) {
        int r = idx >> 6, c = idx & 63;
        o[idx] = __float2bfloat16(c < 40 ? f[(size_t)r * 40 + c] : 0.f);
    }
}

// ---------------------------------------------------------------------------
// bf16 MFMA GEMM: C[row, ccol+n] = act( sum_k A[grow(row), k] * W[n][k] + bias[n] )
//  - tile 128x64, BK=32, 256 threads (4 waves; wave w: rows w*32..w*32+31, all 64 cols)
//  - A,W staged via global_load_lds(16B) with pre-swizzled source (granule XOR (row>>1)&3)
//  - dc>0: conv mode, K=2*dc; k<dc reads past row (t-gdil clamped), else current row
// ---------------------------------------------------------------------------
__global__ __launch_bounds__(256) void mm_bf16(
    const __hip_bfloat16* __restrict__ A, int lda,
    const __hip_bfloat16* __restrict__ W, int ldw,
    const float* __restrict__ bias,
    void* __restrict__ Cout, int ldc, int ccol, int N, int K,
    int dc, int gdil, int act, int outbf)
{
    __shared__ __align__(16) unsigned short As[128 * 32];
    __shared__ __align__(16) unsigned short Ws[64 * 32];

    const int tid  = threadIdx.x;
    const int w    = tid >> 6;
    const int lane = tid & 63;
    const int m0   = blockIdx.x * 128;
    const int n0   = blockIdx.y * 64;

    f32x4 acc[2][4];
#pragma unroll
    for (int m = 0; m < 2; ++m)
#pragma unroll
        for (int n = 0; n < 4; ++n) acc[m][n] = (f32x4){0.f, 0.f, 0.f, 0.f};

    const int ksteps = K >> 5;
    for (int kc = 0; kc < ksteps; ++kc) {
        const int k0 = kc << 5;
#pragma unroll
        for (int it = 0; it < 2; ++it) {
            int s  = it * 256 + w * 64 + lane;
            int rl = s >> 2, g = s & 3;
            int gq = g ^ ((rl >> 1) & 3);
            int grow = m0 + rl;
            int gcol = k0 + gq * 8;
            if (dc > 0) {
                if (k0 < dc) {
                    int t = grow & (T_STEPS - 1);
                    int tp = t - gdil; if (tp < 0) tp = 0;
                    grow = (grow & ~(T_STEPS - 1)) | tp;
                } else {
                    gcol -= dc;
                }
            }
            __builtin_amdgcn_global_load_lds(
                (const __attribute__((address_space(1))) void*)(A + (size_t)grow * lda + gcol),
                (__attribute__((address_space(3))) void*)(As + (size_t)(it * 256 + w * 64) * 8),
                16, 0, 0);
        }
        {
            int s  = w * 64 + lane;
            int rl = s >> 2, g = s & 3;
            int gq = g ^ ((rl >> 1) & 3);
            __builtin_amdgcn_global_load_lds(
                (const __attribute__((address_space(1))) void*)(W + (size_t)(n0 + rl) * ldw + k0 + gq * 8),
                (__attribute__((address_space(3))) void*)(Ws + (size_t)(w * 64) * 8),
                16, 0, 0);
        }
        __syncthreads();

        const int q = lane >> 4, li = lane & 15;
        bf16x8 af[2], wf[4];
#pragma unroll
        for (int m = 0; m < 2; ++m) {
            int r = w * 32 + m * 16 + li;
            af[m] = *(const bf16x8*)(As + (size_t)(r * 4 + (q ^ ((r >> 1) & 3))) * 8);
        }
#pragma unroll
        for (int n = 0; n < 4; ++n) {
            int r = n * 16 + li;
            wf[n] = *(const bf16x8*)(Ws + (size_t)(r * 4 + (q ^ ((r >> 1) & 3))) * 8);
        }
#pragma unroll
        for (int m = 0; m < 2; ++m)
#pragma unroll
            for (int n = 0; n < 4; ++n)
                acc[m][n] = __builtin_amdgcn_mfma_f32_16x16x32_bf16(af[m], wf[n], acc[m][n], 0, 0, 0);
        __syncthreads();
    }

    const int q = lane >> 4, li = lane & 15;
#pragma unroll
    for (int m = 0; m < 2; ++m) {
#pragma unroll
        for (int n = 0; n < 4; ++n) {
            int col = n0 + n * 16 + li;
            if (col < N) {
                float bv = bias ? bias[col] : 0.f;
#pragma unroll
                for (int j = 0; j < 4; ++j) {
                    int row = m0 + w * 32 + m * 16 + q * 4 + j;
                    float v = acc[m][n][j] + bv;
                    if (act) v = fast_tanh(v);
                    if (outbf)
                        ((__hip_bfloat16*)Cout)[(size_t)row * ldc + ccol + col] = __float2bfloat16(v);
                    else
                        ((float*)Cout)[(size_t)row * ldc + ccol + col] = v;
                }
            }
        }
    }
}

// ---------------------------------------------------------------------------
// GRU scan, one wave (64 lanes) per batch, ZERO barriers.
// Lane l owns h[l]; whh rows l, 64+l, 128+l (192 f32) live in VGPRs.
// __launch_bounds__(64, 1): min 1 wave/EU -> full 512-VGPR budget, no spill.
// h broadcast via LDS same-address float4 reads (wave64 lockstep + lgkmcnt).
// Depth-2 xp prefetch covers HBM latency (~900cy) with ~2 steps of work.
// ---------------------------------------------------------------------------
__global__ __launch_bounds__(64, 1) void gru_scan_kernel(
    const float* __restrict__ xp,    // [B*T, 192] = x@wih^T + bih (fp32)
    const float* __restrict__ whh,   // [192, 64]
    const float* __restrict__ bhh,   // [192]
    __hip_bfloat16* __restrict__ xout, int ldx, int ccol)
{
    __shared__ __align__(16) float hs[64];

    const int b = blockIdx.x;
    const int l = threadIdx.x;

    float wr[64], wz[64], wn[64];
#pragma unroll
    for (int k = 0; k < 64; ++k) wr[k] = whh[(size_t)l * 64 + k];
#pragma unroll
    for (int k = 0; k < 64; ++k) wz[k] = whh[(size_t)(64 + l) * 64 + k];
#pragma unroll
    for (int k = 0; k < 64; ++k) wn[k] = whh[(size_t)(128 + l) * 64 + k];
    const float bhr = bhh[l], bhz = bhh[64 + l], bhn = bhh[128 + l];

    const float* xpb = xp + (size_t)b * T_STEPS * 192;
    __hip_bfloat16* xob = xout + (size_t)b * T_STEPS * ldx + ccol + l;

    float hreg = 0.f;
    // depth-2 prefetch pipeline: (xr0,..) = step t, (xr1,..) = step t+1
    float xr0 = xpb[l],       xz0 = xpb[64 + l],  xn0 = xpb[128 + l];
    float xr1 = xpb[192 + l], xz1 = xpb[256 + l], xn1 = xpb[320 + l];

    for (int t = 0; t < T_STEPS; ++t) {
        hs[l] = hreg;

        // prefetch step t+2 (lands ~2 steps later; covers HBM latency)
        float nr = 0.f, nz = 0.f, nn = 0.f;
        if (t + 2 < T_STEPS) {
            const float* p = xpb + (size_t)(t + 2) * 192;
            nr = p[l]; nz = p[64 + l]; nn = p[128 + l];
        }

        // gate dots over h (broadcast reads; 6 interleaved fmac chains)
        float ar0 = 0.f, ar1 = 0.f, az0 = 0.f, az1 = 0.f, an0 = 0.f, an1 = 0.f;
        const float4* h4 = (const float4*)hs;
#pragma unroll
        for (int q = 0; q < 16; ++q) {
            float4 hv = h4[q];
            ar0 += wr[4 * q + 0] * hv.x + wr[4 * q + 1] * hv.y;
            ar1 += wr[4 * q + 2] * hv.z + wr[4 * q + 3] * hv.w;
            az0 += wz[4 * q + 0] * hv.x + wz[4 * q + 1] * hv.y;
            az1 += wz[4 * q + 2] * hv.z + wz[4 * q + 3] * hv.w;
            an0 += wn[4 * q + 0] * hv.x + wn[4 * q + 1] * hv.y;
            an1 += wn[4 * q + 2] * hv.z + wn[4 * q + 3] * hv.w;
        }

        float pr = xr0 + ar0 + ar1 + bhr;
        float pz = xz0 + az0 + az1 + bhz;
        float r = __builtin_amdgcn_rcpf(1.f + __expf(-pr));
        float z = __builtin_amdgcn_rcpf(1.f + __expf(-pz));
        float pn = xn0 + r * (an0 + an1 + bhn);
        // tanh(pn) = 1 - 2/(exp(2*pn)+1); exp overflow->inf->rcp 0 saturates correctly
        float th = 1.f - 2.f * __builtin_amdgcn_rcpf(__expf(2.f * pn) + 1.f);
        hreg = th + z * (hreg - th);

        xob[(size_t)t * ldx] = __float2bfloat16(hreg);
        xr0 = xr1; xz0 = xz1; xn0 = xn1;
        xr1 = nr;  xz1 = nz;  xn1 = nn;
    }
}

extern "C" void kernel_launch(void* const* d_in, const int* in_sizes, int n_in,
                              void* d_out, int out_size, void* d_ws, size_t ws_size,
                              hipStream_t stream) {
    const float* features = (const float*)d_in[0];
    const float* d1_w = (const float*)d_in[1];
    const float* d1_b = (const float*)d_in[2];
    const float* z_w  = (const float*)d_in[33];
    const float* z_b  = (const float*)d_in[34];
    const float* s1_w = (const float*)d_in[35];
    const float* s1_b = (const float*)d_in[36];
    const float* s2_w = (const float*)d_in[37];
    const float* s2_b = (const float*)d_in[38];

    char* ws = (char*)d_ws;
    __hip_bfloat16* xbf  = (__hip_bfloat16*)ws;                    // [ROWS][544] bf16
    float*          xp   = (float*)(ws + 71303168ull);             // [ROWS][192] f32
    __hip_bfloat16* fbf  = (__hip_bfloat16*)(ws + 121634816ull);   // [ROWS][64] bf16
    __hip_bfloat16* s1b  = (__hip_bfloat16*)(ws + 130023424ull);   // [ROWS][128] bf16
    __hip_bfloat16* wbuf = (__hip_bfloat16*)(ws + 146800640ull);   // weights bf16

    float* zout = (float*)d_out;                 // [ROWS][80]
    float* sout = zout + (size_t)ROWS * 80;      // [ROWS][24]

    const int gru_in[5] = {64, 160, 256, 352, 448};
    const int dil[5]    = {1, 2, 2, 2, 2};

    WTab tab;
    long long off = 0;
    auto add = [&](int i, const float* src, int N, int Npad, int K, int Kpad, int dcv) {
        tab.e[i].src = src; tab.e[i].N = N; tab.e[i].Npad = Npad;
        tab.e[i].K = K; tab.e[i].Kpad = Kpad; tab.e[i].dc = dcv; tab.e[i].off = off;
        off += (long long)Npad * Kpad;
    };
    add(0, d1_w, 64, 64, 40, 64, 0);
    for (int n = 0; n < 5; ++n)
        add(1 + n, (const float*)d_in[3 + n * 4], 192, 192, gru_in[n], gru_in[n], 0);
    for (int n = 0; n < 5; ++n) {
        int dcv = gru_in[n] + 64;
        add(6 + n, (const float*)d_in[23 + n * 2], 32, 64, 2 * dcv, 2 * dcv, dcv);
    }
    add(11, z_w, 80, 128, 544, 544, 0);
    add(12, s1_w, 128, 128, 544, 544, 0);
    add(13, s2_w, 24, 64, 128, 128, 0);

    prep_weights<<<dim3(14, 16), 256, 0, stream>>>(tab, wbuf);
    prep_features<<<2048, 256, 0, stream>>>(features, fbf);

    // d1: xbf[:,0:64] = tanh(fbf @ d1_w^T + b)
    mm_bf16<<<dim3(512, 1), 256, 0, stream>>>(
        fbf, 64, wbuf + tab.e[0].off, 64, d1_b, xbf, XW, 0, 64, 64, 0, 0, 1, 1);

    for (int n = 0; n < 5; ++n) {
        const float* whh = (const float*)d_in[3 + n * 4 + 1];
        const float* bih = (const float*)d_in[3 + n * 4 + 2];
        const float* bhh = (const float*)d_in[3 + n * 4 + 3];
        const float* cb  = (const float*)d_in[23 + n * 2 + 1];
        const int din = gru_in[n];
        const int dcv = din + 64;

        // xp = xbf[:,0:din] @ wih^T + bih   (fp32 out)
        mm_bf16<<<dim3(512, 3), 256, 0, stream>>>(
            xbf, XW, wbuf + tab.e[1 + n].off, din, bih, xp, 192, 0, 192, din, 0, 0, 0, 0);

        // sequential GRU scan -> xbf[:, din:din+64]
        gru_scan_kernel<<<dim3(128), dim3(64), 0, stream>>>(xp, whh, bhh, xbf, XW, din);

        // conv (both taps, one GEMM over K=2*dcv) -> xbf[:, dcv:dcv+32]
        mm_bf16<<<dim3(512, 1), 256, 0, stream>>>(
            xbf, XW, wbuf + tab.e[6 + n].off, 2 * dcv, cb, xbf, XW, dcv, 32, 2 * dcv,
            dcv, dil[n], 1, 1);
    }

    // z = xbf @ z_w^T + z_b (fp32 out)
    mm_bf16<<<dim3(512, 2), 256, 0, stream>>>(
        xbf, XW, wbuf + tab.e[11].off, 544, z_b, zout, 80, 0, 80, 544, 0, 0, 0, 0);
    // s1 = tanh(xbf @ s1_w^T + s1_b) (bf16)
    mm_bf16<<<dim3(512, 2), 256, 0, stream>>>(
        xbf, XW, wbuf + tab.e[12].off, 544, s1_b, s1b, 128, 0, 128, 544, 0, 0, 1, 1);
    // states = tanh(s1b @ s2_w^T + s2_b) (fp32 out)
    mm_bf16<<<dim3(512, 1), 256, 0, stream>>>(
        s1b, 128, wbuf + tab.e[13].off, 128, s2_b, sout, 24, 0, 24, 128, 0, 0, 1, 0);
}

// Round 6
// 2434.418 us; speedup vs baseline: 1.3391x; 1.3391x over previous
//
#include <hip/hip_runtime.h>
#include <hip/hip_bf16.h>
#include <cstddef>

#define T_STEPS 512
#define ROWS    65536      // B*T = 128*512
#define XW      544        // full feature width

typedef __attribute__((ext_vector_type(8))) short bf16x8;
typedef __attribute__((ext_vector_type(4))) float f32x4;
typedef __attribute__((ext_vector_type(16))) float f32x16;

__device__ __forceinline__ float fast_tanh(float x) {
    x = fminf(fmaxf(x, -15.f), 15.f);
    float e = __expf(2.f * x);
    return (e - 1.f) / (e + 1.f);
}

// ---------------------------------------------------------------------------
// Weight prep: fp32 -> bf16, layout [Npad][Kpad] row-major, zero padded.
// mode dc>0: conv weight src [N][dc][2] -> dst[n][k] = k<dc ? w[n][k][0] : w[n][k-dc][1]
// ---------------------------------------------------------------------------
struct WDesc { const float* src; int N; int Npad; int K; int Kpad; int dc; long long off; };
struct WTab  { WDesc e[14]; };

__global__ __launch_bounds__(256) void prep_weights(WTab tab, __hip_bfloat16* __restrict__ dst) {
    WDesc d = tab.e[blockIdx.x];
    const int total = d.Npad * d.Kpad;
    for (int idx = blockIdx.y * blockDim.x + threadIdx.x; idx < total;
         idx += gridDim.y * blockDim.x) {
        int n = idx / d.Kpad;
        int k = idx - n * d.Kpad;
        float v = 0.f;
        if (n < d.N && k < d.K) {
            if (d.dc > 0)
                v = (k < d.dc) ? d.src[(n * d.dc + k) * 2]
                               : d.src[(n * d.dc + (k - d.dc)) * 2 + 1];
            else
                v = d.src[(size_t)n * d.K + k];
        }
        dst[d.off + idx] = __float2bfloat16(v);
    }
}

// features [ROWS][40] fp32 -> fbf [ROWS][64] bf16 (zero padded)
__global__ __launch_bounds__(256) void prep_features(const float* __restrict__ f,
                                                     __hip_bfloat16* __restrict__ o) {
    for (int idx = blockIdx.x * blockDim.x + threadIdx.x; idx < ROWS * 64;
         idx += gridDim.x * blockDim.x) {
        int r = idx >> 6, c = idx & 63;
        o[idx] = __float2bfloat16(c < 40 ? f[(size_t)r * 40 + c] : 0.f);
    }
}

// ---------------------------------------------------------------------------
// bf16 MFMA GEMM: C[row, ccol+n] = act( sum_k A[grow(row), k] * W[n][k] + bias[n] )
//  - tile 128x64, BK=32, 256 threads (4 waves; wave w: rows w*32..w*32+31, all 64 cols)
//  - A,W staged via global_load_lds(16B) with pre-swizzled source (granule XOR (row>>1)&3)
//  - dc>0: conv mode, K=2*dc; k<dc reads past row (t-gdil clamped), else current row
// ---------------------------------------------------------------------------
__global__ __launch_bounds__(256) void mm_bf16(
    const __hip_bfloat16* __restrict__ A, int lda,
    const __hip_bfloat16* __restrict__ W, int ldw,
    const float* __restrict__ bias,
    void* __restrict__ Cout, int ldc, int ccol, int N, int K,
    int dc, int gdil, int act, int outbf)
{
    __shared__ __align__(16) unsigned short As[128 * 32];
    __shared__ __align__(16) unsigned short Ws[64 * 32];

    const int tid  = threadIdx.x;
    const int w    = tid >> 6;
    const int lane = tid & 63;
    const int m0   = blockIdx.x * 128;
    const int n0   = blockIdx.y * 64;

    f32x4 acc[2][4];
#pragma unroll
    for (int m = 0; m < 2; ++m)
#pragma unroll
        for (int n = 0; n < 4; ++n) acc[m][n] = (f32x4){0.f, 0.f, 0.f, 0.f};

    const int ksteps = K >> 5;
    for (int kc = 0; kc < ksteps; ++kc) {
        const int k0 = kc << 5;
#pragma unroll
        for (int it = 0; it < 2; ++it) {
            int s  = it * 256 + w * 64 + lane;
            int rl = s >> 2, g = s & 3;
            int gq = g ^ ((rl >> 1) & 3);
            int grow = m0 + rl;
            int gcol = k0 + gq * 8;
            if (dc > 0) {
                if (k0 < dc) {
                    int t = grow & (T_STEPS - 1);
                    int tp = t - gdil; if (tp < 0) tp = 0;
                    grow = (grow & ~(T_STEPS - 1)) | tp;
                } else {
                    gcol -= dc;
                }
            }
            __builtin_amdgcn_global_load_lds(
                (const __attribute__((address_space(1))) void*)(A + (size_t)grow * lda + gcol),
                (__attribute__((address_space(3))) void*)(As + (size_t)(it * 256 + w * 64) * 8),
                16, 0, 0);
        }
        {
            int s  = w * 64 + lane;
            int rl = s >> 2, g = s & 3;
            int gq = g ^ ((rl >> 1) & 3);
            __builtin_amdgcn_global_load_lds(
                (const __attribute__((address_space(1))) void*)(W + (size_t)(n0 + rl) * ldw + k0 + gq * 8),
                (__attribute__((address_space(3))) void*)(Ws + (size_t)(w * 64) * 8),
                16, 0, 0);
        }
        __syncthreads();

        const int q = lane >> 4, li = lane & 15;
        bf16x8 af[2], wf[4];
#pragma unroll
        for (int m = 0; m < 2; ++m) {
            int r = w * 32 + m * 16 + li;
            af[m] = *(const bf16x8*)(As + (size_t)(r * 4 + (q ^ ((r >> 1) & 3))) * 8);
        }
#pragma unroll
        for (int n = 0; n < 4; ++n) {
            int r = n * 16 + li;
            wf[n] = *(const bf16x8*)(Ws + (size_t)(r * 4 + (q ^ ((r >> 1) & 3))) * 8);
        }
#pragma unroll
        for (int m = 0; m < 2; ++m)
#pragma unroll
            for (int n = 0; n < 4; ++n)
                acc[m][n] = __builtin_amdgcn_mfma_f32_16x16x32_bf16(af[m], wf[n], acc[m][n], 0, 0, 0);
        __syncthreads();
    }

    const int q = lane >> 4, li = lane & 15;
#pragma unroll
    for (int m = 0; m < 2; ++m) {
#pragma unroll
        for (int n = 0; n < 4; ++n) {
            int col = n0 + n * 16 + li;
            if (col < N) {
                float bv = bias ? bias[col] : 0.f;
#pragma unroll
                for (int j = 0; j < 4; ++j) {
                    int row = m0 + w * 32 + m * 16 + q * 4 + j;
                    float v = acc[m][n][j] + bv;
                    if (act) v = fast_tanh(v);
                    if (outbf)
                        ((__hip_bfloat16*)Cout)[(size_t)row * ldc + ccol + col] = __float2bfloat16(v);
                    else
                        ((float*)Cout)[(size_t)row * ldc + ccol + col] = v;
                }
            }
        }
    }
}

// ---------------------------------------------------------------------------
// GRU scan, one wave (64 lanes) per batch, ZERO barriers.
// Weights held in 12 NAMED f32x16 vectors (192 VGPRs, constant subscripts
// only) -- defeats hipcc's refusal to promote C-arrays (R3/R5: VGPR=136 =>
// scratch reloads dominated). h broadcast via LDS same-address float4 reads.
// ---------------------------------------------------------------------------
__global__ __launch_bounds__(64, 1) void gru_scan_kernel(
    const float* __restrict__ xp,    // [B*T, 192] = x@wih^T + bih (fp32)
    const float* __restrict__ whh,   // [192, 64]
    const float* __restrict__ bhh,   // [192]
    __hip_bfloat16* __restrict__ xout, int ldx, int ccol)
{
    __shared__ __align__(16) float hs[64];

    const int b = blockIdx.x;
    const int l = threadIdx.x;

    f32x16 wrA, wrB, wrC, wrD, wzA, wzB, wzC, wzD, wnA, wnB, wnC, wnD;

#define PACK16(V, _p, base)                                                     \
    { float4 _a = (_p)[base], _b = (_p)[base + 1], _c = (_p)[base + 2],         \
             _d = (_p)[base + 3];                                               \
      V = (f32x16){_a.x,_a.y,_a.z,_a.w,_b.x,_b.y,_b.z,_b.w,                     \
                   _c.x,_c.y,_c.z,_c.w,_d.x,_d.y,_d.z,_d.w}; }

    {
        const float4* p0 = (const float4*)(whh + (size_t)l * 64);
        PACK16(wrA, p0, 0); PACK16(wrB, p0, 4); PACK16(wrC, p0, 8); PACK16(wrD, p0, 12);
        const float4* p1 = (const float4*)(whh + (size_t)(64 + l) * 64);
        PACK16(wzA, p1, 0); PACK16(wzB, p1, 4); PACK16(wzC, p1, 8); PACK16(wzD, p1, 12);
        const float4* p2 = (const float4*)(whh + (size_t)(128 + l) * 64);
        PACK16(wnA, p2, 0); PACK16(wnB, p2, 4); PACK16(wnC, p2, 8); PACK16(wnD, p2, 12);
    }
    const float bhr = bhh[l], bhz = bhh[64 + l], bhn = bhh[128 + l];

    const float* xpb = xp + (size_t)b * T_STEPS * 192;
    __hip_bfloat16* xob = xout + (size_t)b * T_STEPS * ldx + ccol + l;

    float hreg = 0.f;
    float xr0 = xpb[l],       xz0 = xpb[64 + l],  xn0 = xpb[128 + l];
    float xr1 = xpb[192 + l], xz1 = xpb[256 + l], xn1 = xpb[320 + l];

    for (int t = 0; t < T_STEPS; ++t) {
        hs[l] = hreg;

        // prefetch step t+2
        float nr = 0.f, nz = 0.f, nn = 0.f;
        if (t + 2 < T_STEPS) {
            const float* p = xpb + (size_t)(t + 2) * 192;
            nr = p[l]; nz = p[64 + l]; nn = p[128 + l];
        }

        const float4* h4 = (const float4*)hs;
        float ar0 = 0.f, ar1 = 0.f, az0 = 0.f, az1 = 0.f, an0 = 0.f, an1 = 0.f;

#define DOTQ(V, qq, hv) (V[4*(qq)+0]*hv.x + V[4*(qq)+1]*hv.y +                  \
                         V[4*(qq)+2]*hv.z + V[4*(qq)+3]*hv.w)
#pragma unroll
        for (int q = 0; q < 4; ++q) {
            float4 hv = h4[q];
            ar0 += DOTQ(wrA, q, hv); az0 += DOTQ(wzA, q, hv); an0 += DOTQ(wnA, q, hv);
        }
#pragma unroll
        for (int q = 0; q < 4; ++q) {
            float4 hv = h4[4 + q];
            ar1 += DOTQ(wrB, q, hv); az1 += DOTQ(wzB, q, hv); an1 += DOTQ(wnB, q, hv);
        }
#pragma unroll
        for (int q = 0; q < 4; ++q) {
            float4 hv = h4[8 + q];
            ar0 += DOTQ(wrC, q, hv); az0 += DOTQ(wzC, q, hv); an0 += DOTQ(wnC, q, hv);
        }
#pragma unroll
        for (int q = 0; q < 4; ++q) {
            float4 hv = h4[12 + q];
            ar1 += DOTQ(wrD, q, hv); az1 += DOTQ(wzD, q, hv); an1 += DOTQ(wnD, q, hv);
        }

        float pr = xr0 + ar0 + ar1 + bhr;
        float pz = xz0 + az0 + az1 + bhz;
        float r = __builtin_amdgcn_rcpf(1.f + __expf(-pr));
        float z = __builtin_amdgcn_rcpf(1.f + __expf(-pz));
        float pn = xn0 + r * (an0 + an1 + bhn);
        // tanh(pn) = 1 - 2/(exp(2*pn)+1); exp overflow->inf->rcp 0 saturates correctly
        float th = 1.f - 2.f * __builtin_amdgcn_rcpf(__expf(2.f * pn) + 1.f);
        hreg = th + z * (hreg - th);

        xob[(size_t)t * ldx] = __float2bfloat16(hreg);
        xr0 = xr1; xz0 = xz1; xn0 = xn1;
        xr1 = nr;  xz1 = nz;  xn1 = nn;
    }
}

extern "C" void kernel_launch(void* const* d_in, const int* in_sizes, int n_in,
                              void* d_out, int out_size, void* d_ws, size_t ws_size,
                              hipStream_t stream) {
    const float* features = (const float*)d_in[0];
    const float* d1_w = (const float*)d_in[1];
    const float* d1_b = (const float*)d_in[2];
    const float* z_w  = (const float*)d_in[33];
    const float* z_b  = (const float*)d_in[34];
    const float* s1_w = (const float*)d_in[35];
    const float* s1_b = (const float*)d_in[36];
    const float* s2_w = (const float*)d_in[37];
    const float* s2_b = (const float*)d_in[38];

    char* ws = (char*)d_ws;
    __hip_bfloat16* xbf  = (__hip_bfloat16*)ws;                    // [ROWS][544] bf16
    float*          xp   = (float*)(ws + 71303168ull);             // [ROWS][192] f32
    __hip_bfloat16* fbf  = (__hip_bfloat16*)(ws + 121634816ull);   // [ROWS][64] bf16
    __hip_bfloat16* s1b  = (__hip_bfloat16*)(ws + 130023424ull);   // [ROWS][128] bf16
    __hip_bfloat16* wbuf = (__hip_bfloat16*)(ws + 146800640ull);   // weights bf16

    float* zout = (float*)d_out;                 // [ROWS][80]
    float* sout = zout + (size_t)ROWS * 80;      // [ROWS][24]

    const int gru_in[5] = {64, 160, 256, 352, 448};
    const int dil[5]    = {1, 2, 2, 2, 2};

    WTab tab;
    long long off = 0;
    auto add = [&](int i, const float* src, int N, int Npad, int K, int Kpad, int dcv) {
        tab.e[i].src = src; tab.e[i].N = N; tab.e[i].Npad = Npad;
        tab.e[i].K = K; tab.e[i].Kpad = Kpad; tab.e[i].dc = dcv; tab.e[i].off = off;
        off += (long long)Npad * Kpad;
    };
    add(0, d1_w, 64, 64, 40, 64, 0);
    for (int n = 0; n < 5; ++n)
        add(1 + n, (const float*)d_in[3 + n * 4], 192, 192, gru_in[n], gru_in[n], 0);
    for (int n = 0; n < 5; ++n) {
        int dcv = gru_in[n] + 64;
        add(6 + n, (const float*)d_in[23 + n * 2], 32, 64, 2 * dcv, 2 * dcv, dcv);
    }
    add(11, z_w, 80, 128, 544, 544, 0);
    add(12, s1_w, 128, 128, 544, 544, 0);
    add(13, s2_w, 24, 64, 128, 128, 0);

    prep_weights<<<dim3(14, 16), 256, 0, stream>>>(tab, wbuf);
    prep_features<<<2048, 256, 0, stream>>>(features, fbf);

    // d1: xbf[:,0:64] = tanh(fbf @ d1_w^T + b)
    mm_bf16<<<dim3(512, 1), 256, 0, stream>>>(
        fbf, 64, wbuf + tab.e[0].off, 64, d1_b, xbf, XW, 0, 64, 64, 0, 0, 1, 1);

    for (int n = 0; n < 5; ++n) {
        const float* whh = (const float*)d_in[3 + n * 4 + 1];
        const float* bih = (const float*)d_in[3 + n * 4 + 2];
        const float* bhh = (const float*)d_in[3 + n * 4 + 3];
        const float* cb  = (const float*)d_in[23 + n * 2 + 1];
        const int din = gru_in[n];
        const int dcv = din + 64;

        // xp = xbf[:,0:din] @ wih^T + bih   (fp32 out)
        mm_bf16<<<dim3(512, 3), 256, 0, stream>>>(
            xbf, XW, wbuf + tab.e[1 + n].off, din, bih, xp, 192, 0, 192, din, 0, 0, 0, 0);

        // sequential GRU scan -> xbf[:, din:din+64]
        gru_scan_kernel<<<dim3(128), dim3(64), 0, stream>>>(xp, whh, bhh, xbf, XW, din);

        // conv (both taps, one GEMM over K=2*dcv) -> xbf[:, dcv:dcv+32]
        mm_bf16<<<dim3(512, 1), 256, 0, stream>>>(
            xbf, XW, wbuf + tab.e[6 + n].off, 2 * dcv, cb, xbf, XW, dcv, 32, 2 * dcv,
            dcv, dil[n], 1, 1);
    }

    // z = xbf @ z_w^T + z_b (fp32 out)
    mm_bf16<<<dim3(512, 2), 256, 0, stream>>>(
        xbf, XW, wbuf + tab.e[11].off, 544, z_b, zout, 80, 0, 80, 544, 0, 0, 0, 0);
    // s1 = tanh(xbf @ s1_w^T + s1_b) (bf16)
    mm_bf16<<<dim3(512, 2), 256, 0, stream>>>(
        xbf, XW, wbuf + tab.e[12].off, 544, s1_b, s1b, 128, 0, 128, 544, 0, 0, 1, 1);
    // states = tanh(s1b @ s2_w^T + s2_b) (fp32 out)
    mm_bf16<<<dim3(512, 1), 256, 0, stream>>>(
        s1b, 128, wbuf + tab.e[13].off, 128, s2_b, sout, 24, 0, 24, 128, 0, 0, 1, 0);
}

// Round 7
// 1363.286 us; speedup vs baseline: 2.3913x; 1.7857x over previous
//
#include <hip/hip_runtime.h>
#include <hip/hip_bf16.h>
#include <cstddef>

#define T_STEPS 512
#define ROWS    65536      // B*T = 128*512
#define XW      544        // full feature width

typedef __attribute__((ext_vector_type(8))) short bf16x8;
typedef __attribute__((ext_vector_type(4))) float f32x4;
typedef __attribute__((ext_vector_type(8))) unsigned int u32x8;
typedef _Float16 half_t;
typedef __attribute__((ext_vector_type(2))) _Float16 half2_t;

__device__ __forceinline__ float fast_tanh(float x) {
    x = fminf(fmaxf(x, -15.f), 15.f);
    float e = __expf(2.f * x);
    return (e - 1.f) / (e + 1.f);
}

// ---------------------------------------------------------------------------
// Weight prep: fp32 -> bf16, layout [Npad][Kpad] row-major, zero padded.
// mode dc>0: conv weight src [N][dc][2] -> dst[n][k] = k<dc ? w[n][k][0] : w[n][k-dc][1]
// ---------------------------------------------------------------------------
struct WDesc { const float* src; int N; int Npad; int K; int Kpad; int dc; long long off; };
struct WTab  { WDesc e[14]; };

__global__ __launch_bounds__(256) void prep_weights(WTab tab, __hip_bfloat16* __restrict__ dst) {
    WDesc d = tab.e[blockIdx.x];
    const int total = d.Npad * d.Kpad;
    for (int idx = blockIdx.y * blockDim.x + threadIdx.x; idx < total;
         idx += gridDim.y * blockDim.x) {
        int n = idx / d.Kpad;
        int k = idx - n * d.Kpad;
        float v = 0.f;
        if (n < d.N && k < d.K) {
            if (d.dc > 0)
                v = (k < d.dc) ? d.src[(n * d.dc + k) * 2]
                               : d.src[(n * d.dc + (k - d.dc)) * 2 + 1];
            else
                v = d.src[(size_t)n * d.K + k];
        }
        dst[d.off + idx] = __float2bfloat16(v);
    }
}

// features [ROWS][40] fp32 -> fbf [ROWS][64] bf16 (zero padded)
__global__ __launch_bounds__(256) void prep_features(const float* __restrict__ f,
                                                     __hip_bfloat16* __restrict__ o) {
    for (int idx = blockIdx.x * blockDim.x + threadIdx.x; idx < ROWS * 64;
         idx += gridDim.x * blockDim.x) {
        int r = idx >> 6, c = idx & 63;
        o[idx] = __float2bfloat16(c < 40 ? f[(size_t)r * 40 + c] : 0.f);
    }
}

// ---------------------------------------------------------------------------
// bf16 MFMA GEMM: C[row, ccol+n] = act( sum_k A[grow(row), k] * W[n][k] + bias[n] )
//  - tile 128x64, BK=32, 256 threads (4 waves; wave w: rows w*32..w*32+31, all 64 cols)
//  - A,W staged via global_load_lds(16B) with pre-swizzled source (granule XOR (row>>1)&3)
//  - dc>0: conv mode, K=2*dc; k<dc reads past row (t-gdil clamped), else current row
// ---------------------------------------------------------------------------
__global__ __launch_bounds__(256) void mm_bf16(
    const __hip_bfloat16* __restrict__ A, int lda,
    const __hip_bfloat16* __restrict__ W, int ldw,
    const float* __restrict__ bias,
    void* __restrict__ Cout, int ldc, int ccol, int N, int K,
    int dc, int gdil, int act, int outbf)
{
    __shared__ __align__(16) unsigned short As[128 * 32];
    __shared__ __align__(16) unsigned short Ws[64 * 32];

    const int tid  = threadIdx.x;
    const int w    = tid >> 6;
    const int lane = tid & 63;
    const int m0   = blockIdx.x * 128;
    const int n0   = blockIdx.y * 64;

    f32x4 acc[2][4];
#pragma unroll
    for (int m = 0; m < 2; ++m)
#pragma unroll
        for (int n = 0; n < 4; ++n) acc[m][n] = (f32x4){0.f, 0.f, 0.f, 0.f};

    const int ksteps = K >> 5;
    for (int kc = 0; kc < ksteps; ++kc) {
        const int k0 = kc << 5;
#pragma unroll
        for (int it = 0; it < 2; ++it) {
            int s  = it * 256 + w * 64 + lane;
            int rl = s >> 2, g = s & 3;
            int gq = g ^ ((rl >> 1) & 3);
            int grow = m0 + rl;
            int gcol = k0 + gq * 8;
            if (dc > 0) {
                if (k0 < dc) {
                    int t = grow & (T_STEPS - 1);
                    int tp = t - gdil; if (tp < 0) tp = 0;
                    grow = (grow & ~(T_STEPS - 1)) | tp;
                } else {
                    gcol -= dc;
                }
            }
            __builtin_amdgcn_global_load_lds(
                (const __attribute__((address_space(1))) void*)(A + (size_t)grow * lda + gcol),
                (__attribute__((address_space(3))) void*)(As + (size_t)(it * 256 + w * 64) * 8),
                16, 0, 0);
        }
        {
            int s  = w * 64 + lane;
            int rl = s >> 2, g = s & 3;
            int gq = g ^ ((rl >> 1) & 3);
            __builtin_amdgcn_global_load_lds(
                (const __attribute__((address_space(1))) void*)(W + (size_t)(n0 + rl) * ldw + k0 + gq * 8),
                (__attribute__((address_space(3))) void*)(Ws + (size_t)(w * 64) * 8),
                16, 0, 0);
        }
        __syncthreads();

        const int q = lane >> 4, li = lane & 15;
        bf16x8 af[2], wf[4];
#pragma unroll
        for (int m = 0; m < 2; ++m) {
            int r = w * 32 + m * 16 + li;
            af[m] = *(const bf16x8*)(As + (size_t)(r * 4 + (q ^ ((r >> 1) & 3))) * 8);
        }
#pragma unroll
        for (int n = 0; n < 4; ++n) {
            int r = n * 16 + li;
            wf[n] = *(const bf16x8*)(Ws + (size_t)(r * 4 + (q ^ ((r >> 1) & 3))) * 8);
        }
#pragma unroll
        for (int m = 0; m < 2; ++m)
#pragma unroll
            for (int n = 0; n < 4; ++n)
                acc[m][n] = __builtin_amdgcn_mfma_f32_16x16x32_bf16(af[m], wf[n], acc[m][n], 0, 0, 0);
        __syncthreads();
    }

    const int q = lane >> 4, li = lane & 15;
#pragma unroll
    for (int m = 0; m < 2; ++m) {
#pragma unroll
        for (int n = 0; n < 4; ++n) {
            int col = n0 + n * 16 + li;
            if (col < N) {
                float bv = bias ? bias[col] : 0.f;
#pragma unroll
                for (int j = 0; j < 4; ++j) {
                    int row = m0 + w * 32 + m * 16 + q * 4 + j;
                    float v = acc[m][n][j] + bv;
                    if (act) v = fast_tanh(v);
                    if (outbf)
                        ((__hip_bfloat16*)Cout)[(size_t)row * ldc + ccol + col] = __float2bfloat16(v);
                    else
                        ((float*)Cout)[(size_t)row * ldc + ccol + col] = v;
                }
            }
        }
    }
}

// ---------------------------------------------------------------------------
// GRU scan, one wave (64 lanes) per batch, ZERO barriers.
// Weights packed as f16 PAIRS: 96 dwords in 12 named u32x8 vectors (96 VGPRs
// total -- fits hipcc's observed ~150-reg budget, unlike 192 f32 which it
// remats from global every step: R3/R5/R6 all stuck at 136-152 VGPR).
// Dots via v_dot2_f32_f16 (2 MAC/instr). h exchanged through LDS as f16
// pairs; broadcast uint4 reads are conflict-free. asm-opacity pins the
// packed weights against rematerialization.
// ---------------------------------------------------------------------------
__global__ __launch_bounds__(64, 1) void gru_scan_kernel(
    const float* __restrict__ xp,    // [B*T, 192] = x@wih^T + bih (fp32)
    const float* __restrict__ whh,   // [192, 64]
    const float* __restrict__ bhh,   // [192]
    __hip_bfloat16* __restrict__ xout, int ldx, int ccol)
{
    __shared__ __align__(16) unsigned int hs2[32];   // h as packed f16 pairs

    const int b = blockIdx.x;
    const int l = threadIdx.x;

#define PKF2(f2) __builtin_bit_cast(unsigned int, __builtin_amdgcn_cvt_pkrtz((f2).x, (f2).y))
#define PACKV(V, p2, base)                                                      \
    V = (u32x8){ PKF2(p2[(base) + 0]), PKF2(p2[(base) + 1]), PKF2(p2[(base) + 2]), \
                 PKF2(p2[(base) + 3]), PKF2(p2[(base) + 4]), PKF2(p2[(base) + 5]), \
                 PKF2(p2[(base) + 6]), PKF2(p2[(base) + 7]) };

    u32x8 wrA, wrB, wrC, wrD, wzA, wzB, wzC, wzD, wnA, wnB, wnC, wnD;
    {
        const float2* p0 = (const float2*)(whh + (size_t)l * 64);
        PACKV(wrA, p0, 0); PACKV(wrB, p0, 8); PACKV(wrC, p0, 16); PACKV(wrD, p0, 24);
        const float2* p1 = (const float2*)(whh + (size_t)(64 + l) * 64);
        PACKV(wzA, p1, 0); PACKV(wzB, p1, 8); PACKV(wzC, p1, 16); PACKV(wzD, p1, 24);
        const float2* p2 = (const float2*)(whh + (size_t)(128 + l) * 64);
        PACKV(wnA, p2, 0); PACKV(wnB, p2, 8); PACKV(wnC, p2, 16); PACKV(wnD, p2, 24);
    }
    // Pin against rematerialization: values now "come from asm".
    asm volatile("" : "+v"(wrA), "+v"(wrB), "+v"(wrC), "+v"(wrD));
    asm volatile("" : "+v"(wzA), "+v"(wzB), "+v"(wzC), "+v"(wzD));
    asm volatile("" : "+v"(wnA), "+v"(wnB), "+v"(wnC), "+v"(wnD));

    const float bhr = bhh[l], bhz = bhh[64 + l], bhn = bhh[128 + l];

    const float* xpb = xp + (size_t)b * T_STEPS * 192;
    __hip_bfloat16* xob = xout + (size_t)b * T_STEPS * ldx + ccol + l;

    float hreg = 0.f;
    float xr0 = xpb[l],       xz0 = xpb[64 + l],  xn0 = xpb[128 + l];
    float xr1 = xpb[192 + l], xz1 = xpb[256 + l], xn1 = xpb[320 + l];

#if __has_builtin(__builtin_amdgcn_fdot2)
#define D2(V, i, hu, acc) acc = __builtin_amdgcn_fdot2(                         \
        __builtin_bit_cast(half2_t, (unsigned int)V[i]),                        \
        __builtin_bit_cast(half2_t, (unsigned int)(hu)), acc, false)
#else
#define D2(V, i, hu, acc) { half2_t w_ = __builtin_bit_cast(half2_t, (unsigned int)V[i]); \
        half2_t h_ = __builtin_bit_cast(half2_t, (unsigned int)(hu));           \
        acc += (float)w_.x * (float)h_.x + (float)w_.y * (float)h_.y; }
#endif
#define DOT8(V, hv0, hv1, a0, a1)                                               \
    D2(V, 0, hv0.x, a0); D2(V, 1, hv0.y, a1); D2(V, 2, hv0.z, a0); D2(V, 3, hv0.w, a1); \
    D2(V, 4, hv1.x, a0); D2(V, 5, hv1.y, a1); D2(V, 6, hv1.z, a0); D2(V, 7, hv1.w, a1);

    for (int t = 0; t < T_STEPS; ++t) {
        // publish own h as packed f16 (lane l -> 2 bytes; 2 lanes/bank = free)
        ((half_t*)hs2)[l] = (half_t)hreg;

        // prefetch step t+2
        float nr = 0.f, nz = 0.f, nn = 0.f;
        if (t + 2 < T_STEPS) {
            const float* p = xpb + (size_t)(t + 2) * 192;
            nr = p[l]; nz = p[64 + l]; nn = p[128 + l];
        }

        const uint4* h4 = (const uint4*)hs2;
        float ar0 = 0.f, ar1 = 0.f, az0 = 0.f, az1 = 0.f, an0 = 0.f, an1 = 0.f;
        {
            uint4 hv0 = h4[0], hv1 = h4[1];
            DOT8(wrA, hv0, hv1, ar0, ar1);
            DOT8(wzA, hv0, hv1, az0, az1);
            DOT8(wnA, hv0, hv1, an0, an1);
        }
        {
            uint4 hv0 = h4[2], hv1 = h4[3];
            DOT8(wrB, hv0, hv1, ar0, ar1);
            DOT8(wzB, hv0, hv1, az0, az1);
            DOT8(wnB, hv0, hv1, an0, an1);
        }
        {
            uint4 hv0 = h4[4], hv1 = h4[5];
            DOT8(wrC, hv0, hv1, ar0, ar1);
            DOT8(wzC, hv0, hv1, az0, az1);
            DOT8(wnC, hv0, hv1, an0, an1);
        }
        {
            uint4 hv0 = h4[6], hv1 = h4[7];
            DOT8(wrD, hv0, hv1, ar0, ar1);
            DOT8(wzD, hv0, hv1, az0, az1);
            DOT8(wnD, hv0, hv1, an0, an1);
        }

        float pr = xr0 + ar0 + ar1 + bhr;
        float pz = xz0 + az0 + az1 + bhz;
        float r = __builtin_amdgcn_rcpf(1.f + __expf(-pr));
        float z = __builtin_amdgcn_rcpf(1.f + __expf(-pz));
        float pn = xn0 + r * (an0 + an1 + bhn);
        // tanh(pn) = 1 - 2/(exp(2*pn)+1); exp overflow->inf->rcp 0 saturates correctly
        float th = 1.f - 2.f * __builtin_amdgcn_rcpf(__expf(2.f * pn) + 1.f);
        hreg = th + z * (hreg - th);

        xob[(size_t)t * ldx] = __float2bfloat16(hreg);
        xr0 = xr1; xz0 = xz1; xn0 = xn1;
        xr1 = nr;  xz1 = nz;  xn1 = nn;
    }
}

extern "C" void kernel_launch(void* const* d_in, const int* in_sizes, int n_in,
                              void* d_out, int out_size, void* d_ws, size_t ws_size,
                              hipStream_t stream) {
    const float* features = (const float*)d_in[0];
    const float* d1_w = (const float*)d_in[1];
    const float* d1_b = (const float*)d_in[2];
    const float* z_w  = (const float*)d_in[33];
    const float* z_b  = (const float*)d_in[34];
    const float* s1_w = (const float*)d_in[35];
    const float* s1_b = (const float*)d_in[36];
    const float* s2_w = (const float*)d_in[37];
    const float* s2_b = (const float*)d_in[38];

    char* ws = (char*)d_ws;
    __hip_bfloat16* xbf  = (__hip_bfloat16*)ws;                    // [ROWS][544] bf16
    float*          xp   = (float*)(ws + 71303168ull);             // [ROWS][192] f32
    __hip_bfloat16* fbf  = (__hip_bfloat16*)(ws + 121634816ull);   // [ROWS][64] bf16
    __hip_bfloat16* s1b  = (__hip_bfloat16*)(ws + 130023424ull);   // [ROWS][128] bf16
    __hip_bfloat16* wbuf = (__hip_bfloat16*)(ws + 146800640ull);   // weights bf16

    float* zout = (float*)d_out;                 // [ROWS][80]
    float* sout = zout + (size_t)ROWS * 80;      // [ROWS][24]

    const int gru_in[5] = {64, 160, 256, 352, 448};
    const int dil[5]    = {1, 2, 2, 2, 2};

    WTab tab;
    long long off = 0;
    auto add = [&](int i, const float* src, int N, int Npad, int K, int Kpad, int dcv) {
        tab.e[i].src = src; tab.e[i].N = N; tab.e[i].Npad = Npad;
        tab.e[i].K = K; tab.e[i].Kpad = Kpad; tab.e[i].dc = dcv; tab.e[i].off = off;
        off += (long long)Npad * Kpad;
    };
    add(0, d1_w, 64, 64, 40, 64, 0);
    for (int n = 0; n < 5; ++n)
        add(1 + n, (const float*)d_in[3 + n * 4], 192, 192, gru_in[n], gru_in[n], 0);
    for (int n = 0; n < 5; ++n) {
        int dcv = gru_in[n] + 64;
        add(6 + n, (const float*)d_in[23 + n * 2], 32, 64, 2 * dcv, 2 * dcv, dcv);
    }
    add(11, z_w, 80, 128, 544, 544, 0);
    add(12, s1_w, 128, 128, 544, 544, 0);
    add(13, s2_w, 24, 64, 128, 128, 0);

    prep_weights<<<dim3(14, 16), 256, 0, stream>>>(tab, wbuf);
    prep_features<<<2048, 256, 0, stream>>>(features, fbf);

    // d1: xbf[:,0:64] = tanh(fbf @ d1_w^T + b)
    mm_bf16<<<dim3(512, 1), 256, 0, stream>>>(
        fbf, 64, wbuf + tab.e[0].off, 64, d1_b, xbf, XW, 0, 64, 64, 0, 0, 1, 1);

    for (int n = 0; n < 5; ++n) {
        const float* whh = (const float*)d_in[3 + n * 4 + 1];
        const float* bih = (const float*)d_in[3 + n * 4 + 2];
        const float* bhh = (const float*)d_in[3 + n * 4 + 3];
        const float* cb  = (const float*)d_in[23 + n * 2 + 1];
        const int din = gru_in[n];
        const int dcv = din + 64;

        // xp = xbf[:,0:din] @ wih^T + bih   (fp32 out)
        mm_bf16<<<dim3(512, 3), 256, 0, stream>>>(
            xbf, XW, wbuf + tab.e[1 + n].off, din, bih, xp, 192, 0, 192, din, 0, 0, 0, 0);

        // sequential GRU scan -> xbf[:, din:din+64]
        gru_scan_kernel<<<dim3(128), dim3(64), 0, stream>>>(xp, whh, bhh, xbf, XW, din);

        // conv (both taps, one GEMM over K=2*dcv) -> xbf[:, dcv:dcv+32]
        mm_bf16<<<dim3(512, 1), 256, 0, stream>>>(
            xbf, XW, wbuf + tab.e[6 + n].off, 2 * dcv, cb, xbf, XW, dcv, 32, 2 * dcv,
            dcv, dil[n], 1, 1);
    }

    // z = xbf @ z_w^T + z_b (fp32 out)
    mm_bf16<<<dim3(512, 2), 256, 0, stream>>>(
        xbf, XW, wbuf + tab.e[11].off, 544, z_b, zout, 80, 0, 80, 544, 0, 0, 0, 0);
    // s1 = tanh(xbf @ s1_w^T + s1_b) (bf16)
    mm_bf16<<<dim3(512, 2), 256, 0, stream>>>(
        xbf, XW, wbuf + tab.e[12].off, 544, s1_b, s1b, 128, 0, 128, 544, 0, 0, 1, 1);
    // states = tanh(s1b @ s2_w^T + s2_b) (fp32 out)
    mm_bf16<<<dim3(512, 1), 256, 0, stream>>>(
        s1b, 128, wbuf + tab.e[13].off, 128, s2_b, sout, 24, 0, 24, 128, 0, 0, 1, 0);
}

// Round 10
// 1333.328 us; speedup vs baseline: 2.4450x; 1.0225x over previous
//
#include <hip/hip_runtime.h>
#include <hip/hip_bf16.h>
#include <cstddef>

#define T_STEPS 512
#define ROWS    65536      // B*T = 128*512
#define XW      544        // full feature width

typedef __attribute__((ext_vector_type(8))) short bf16x8;
typedef __attribute__((ext_vector_type(4))) float f32x4;
typedef _Float16 half_t;
typedef __attribute__((ext_vector_type(2))) _Float16 half2_t;

__device__ __forceinline__ float fast_tanh(float x) {
    x = fminf(fmaxf(x, -15.f), 15.f);
    float e = __expf(2.f * x);
    return (e - 1.f) / (e + 1.f);
}

// ---------------------------------------------------------------------------
// Weight prep: fp32 -> bf16, layout [Npad][Kpad] row-major, zero padded.
// mode dc>0: conv weight src [N][dc][2] -> dst[n][k] = k<dc ? w[n][k][0] : w[n][k-dc][1]
// ---------------------------------------------------------------------------
struct WDesc { const float* src; int N; int Npad; int K; int Kpad; int dc; long long off; };
struct WTab  { WDesc e[14]; };

__global__ __launch_bounds__(256) void prep_weights(WTab tab, __hip_bfloat16* __restrict__ dst) {
    WDesc d = tab.e[blockIdx.x];
    const int total = d.Npad * d.Kpad;
    for (int idx = blockIdx.y * blockDim.x + threadIdx.x; idx < total;
         idx += gridDim.y * blockDim.x) {
        int n = idx / d.Kpad;
        int k = idx - n * d.Kpad;
        float v = 0.f;
        if (n < d.N && k < d.K) {
            if (d.dc > 0)
                v = (k < d.dc) ? d.src[(n * d.dc + k) * 2]
                               : d.src[(n * d.dc + (k - d.dc)) * 2 + 1];
            else
                v = d.src[(size_t)n * d.K + k];
        }
        dst[d.off + idx] = __float2bfloat16(v);
    }
}

// features [ROWS][40] fp32 -> fbf [ROWS][64] bf16 (zero padded)
__global__ __launch_bounds__(256) void prep_features(const float* __restrict__ f,
                                                     __hip_bfloat16* __restrict__ o) {
    for (int idx = blockIdx.x * blockDim.x + threadIdx.x; idx < ROWS * 64;
         idx += gridDim.x * blockDim.x) {
        int r = idx >> 6, c = idx & 63;
        o[idx] = __float2bfloat16(c < 40 ? f[(size_t)r * 40 + c] : 0.f);
    }
}

// ---------------------------------------------------------------------------
// bf16 MFMA GEMM: C[row, ccol+n] = act( sum_k A[grow(row), k] * W[n][k] + bias[n] )
//  - tile 128x64, BK=32, 256 threads (4 waves; wave w: rows w*32..w*32+31, all 64 cols)
//  - A,W staged via global_load_lds(16B) with pre-swizzled source (granule XOR (row>>1)&3)
//  - dc>0: conv mode, K=2*dc; k<dc reads past row (t-gdil clamped), else current row
// ---------------------------------------------------------------------------
__global__ __launch_bounds__(256) void mm_bf16(
    const __hip_bfloat16* __restrict__ A, int lda,
    const __hip_bfloat16* __restrict__ W, int ldw,
    const float* __restrict__ bias,
    void* __restrict__ Cout, int ldc, int ccol, int N, int K,
    int dc, int gdil, int act, int outbf)
{
    __shared__ __align__(16) unsigned short As[128 * 32];
    __shared__ __align__(16) unsigned short Ws[64 * 32];

    const int tid  = threadIdx.x;
    const int w    = tid >> 6;
    const int lane = tid & 63;
    const int m0   = blockIdx.x * 128;
    const int n0   = blockIdx.y * 64;

    f32x4 acc[2][4];
#pragma unroll
    for (int m = 0; m < 2; ++m)
#pragma unroll
        for (int n = 0; n < 4; ++n) acc[m][n] = (f32x4){0.f, 0.f, 0.f, 0.f};

    const int ksteps = K >> 5;
    for (int kc = 0; kc < ksteps; ++kc) {
        const int k0 = kc << 5;
#pragma unroll
        for (int it = 0; it < 2; ++it) {
            int s  = it * 256 + w * 64 + lane;
            int rl = s >> 2, g = s & 3;
            int gq = g ^ ((rl >> 1) & 3);
            int grow = m0 + rl;
            int gcol = k0 + gq * 8;
            if (dc > 0) {
                if (k0 < dc) {
                    int t = grow & (T_STEPS - 1);
                    int tp = t - gdil; if (tp < 0) tp = 0;
                    grow = (grow & ~(T_STEPS - 1)) | tp;
                } else {
                    gcol -= dc;
                }
            }
            __builtin_amdgcn_global_load_lds(
                (const __attribute__((address_space(1))) void*)(A + (size_t)grow * lda + gcol),
                (__attribute__((address_space(3))) void*)(As + (size_t)(it * 256 + w * 64) * 8),
                16, 0, 0);
        }
        {
            int s  = w * 64 + lane;
            int rl = s >> 2, g = s & 3;
            int gq = g ^ ((rl >> 1) & 3);
            __builtin_amdgcn_global_load_lds(
                (const __attribute__((address_space(1))) void*)(W + (size_t)(n0 + rl) * ldw + k0 + gq * 8),
                (__attribute__((address_space(3))) void*)(Ws + (size_t)(w * 64) * 8),
                16, 0, 0);
        }
        __syncthreads();

        const int q = lane >> 4, li = lane & 15;
        bf16x8 af[2], wf[4];
#pragma unroll
        for (int m = 0; m < 2; ++m) {
            int r = w * 32 + m * 16 + li;
            af[m] = *(const bf16x8*)(As + (size_t)(r * 4 + (q ^ ((r >> 1) & 3))) * 8);
        }
#pragma unroll
        for (int n = 0; n < 4; ++n) {
            int r = n * 16 + li;
            wf[n] = *(const bf16x8*)(Ws + (size_t)(r * 4 + (q ^ ((r >> 1) & 3))) * 8);
        }
#pragma unroll
        for (int m = 0; m < 2; ++m)
#pragma unroll
            for (int n = 0; n < 4; ++n)
                acc[m][n] = __builtin_amdgcn_mfma_f32_16x16x32_bf16(af[m], wf[n], acc[m][n], 0, 0, 0);
        __syncthreads();
    }

    const int q = lane >> 4, li = lane & 15;
#pragma unroll
    for (int m = 0; m < 2; ++m) {
#pragma unroll
        for (int n = 0; n < 4; ++n) {
            int col = n0 + n * 16 + li;
            if (col < N) {
                float bv = bias ? bias[col] : 0.f;
#pragma unroll
                for (int j = 0; j < 4; ++j) {
                    int row = m0 + w * 32 + m * 16 + q * 4 + j;
                    float v = acc[m][n][j] + bv;
                    if (act) v = fast_tanh(v);
                    if (outbf)
                        ((__hip_bfloat16*)Cout)[(size_t)row * ldc + ccol + col] = __float2bfloat16(v);
                    else
                        ((float*)Cout)[(size_t)row * ldc + ccol + col] = v;
                }
            }
        }
    }
}

// ---------------------------------------------------------------------------
// GRU scan, one wave per batch, ZERO barriers.
// Weights live in LDS as a software register file (hipcc refuses to keep
// >~96 dwords in VGPRs: R3/R5/R6/R7 all spilled). Layout wlds[chunk][row]
// (row = gate*64+l, chunk = 8-f16 group): lane stride 16B => conflict-free
// ds_read_b128. Each lane reads only its OWN 3 rows (no sharing; no sync).
// h is exchanged as packed f16 pairs, broadcast uint4 reads (free).
// Dots via v_dot2_f32_f16. Per-step LDS: 24 weight + 8 h reads.
// ---------------------------------------------------------------------------
__global__ __launch_bounds__(64, 1) void gru_scan_kernel(
    const float* __restrict__ xp,    // [B*T, 192] = x@wih^T + bih (fp32)
    const float* __restrict__ whh,   // [192, 64]
    const float* __restrict__ bhh,   // [192]
    __hip_bfloat16* __restrict__ xout, int ldx, int ccol)
{
    __shared__ __align__(16) uint4 wlds[8 * 192];    // [chunk][row] 16B each = 24 KB
    __shared__ __align__(16) unsigned int hs2[32];   // h as packed f16 pairs

    const int b = blockIdx.x;
    const int l = threadIdx.x;

#define PKF2(a, c) __builtin_bit_cast(unsigned int, __builtin_amdgcn_cvt_pkrtz(a, c))

    // pack own 3 rows of whh (f32 -> f16 pairs) into LDS
#pragma unroll
    for (int j = 0; j < 3; ++j) {
        const int row = j * 64 + l;
        const float4* src = (const float4*)(whh + (size_t)row * 64);
#pragma unroll
        for (int c = 0; c < 8; ++c) {
            float4 a = src[2 * c], d = src[2 * c + 1];
            wlds[c * 192 + row] = (uint4){ PKF2(a.x, a.y), PKF2(a.z, a.w),
                                           PKF2(d.x, d.y), PKF2(d.z, d.w) };
        }
    }

    const float bhr = bhh[l], bhz = bhh[64 + l], bhn = bhh[128 + l];

    const float* xpb = xp + (size_t)b * T_STEPS * 192;
    __hip_bfloat16* xob = xout + (size_t)b * T_STEPS * ldx + ccol + l;

    float hreg = 0.f;
    float xr0 = xpb[l],       xz0 = xpb[64 + l],  xn0 = xpb[128 + l];
    float xr1 = xpb[192 + l], xz1 = xpb[256 + l], xn1 = xpb[320 + l];

#if __has_builtin(__builtin_amdgcn_fdot2)
#define D2(wu, hu, acc) acc = __builtin_amdgcn_fdot2(                           \
        __builtin_bit_cast(half2_t, (unsigned int)(wu)),                        \
        __builtin_bit_cast(half2_t, (unsigned int)(hu)), acc, false)
#else
#define D2(wu, hu, acc) { half2_t w_ = __builtin_bit_cast(half2_t, (unsigned int)(wu)); \
        half2_t h_ = __builtin_bit_cast(half2_t, (unsigned int)(hu));           \
        acc += (float)w_.x * (float)h_.x + (float)w_.y * (float)h_.y; }
#endif
#define DOT16(wv, hv, a0, a1)                                                   \
    D2(wv.x, hv.x, a0); D2(wv.y, hv.y, a1); D2(wv.z, hv.z, a0); D2(wv.w, hv.w, a1);

    const uint4* wR = wlds + l;          // + c*192
    const uint4* wZ = wlds + 64 + l;
    const uint4* wN = wlds + 128 + l;
    const uint4* h4 = (const uint4*)hs2;

    for (int t = 0; t < T_STEPS; ++t) {
        // publish own h as packed f16 (2 lanes/bank = free)
        ((half_t*)hs2)[l] = (half_t)hreg;

        // prefetch step t+2
        float nr = 0.f, nz = 0.f, nn = 0.f;
        if (t + 2 < T_STEPS) {
            const float* p = xpb + (size_t)(t + 2) * 192;
            nr = p[l]; nz = p[64 + l]; nn = p[128 + l];
        }

        float ar0 = 0.f, ar1 = 0.f, az0 = 0.f, az1 = 0.f, an0 = 0.f, an1 = 0.f;
#pragma unroll
        for (int c = 0; c < 8; ++c) {
            uint4 hv  = h4[c];          // broadcast (h[8c..8c+7] as f16 pairs)
            uint4 wrv = wR[c * 192];
            uint4 wzv = wZ[c * 192];
            uint4 wnv = wN[c * 192];
            DOT16(wrv, hv, ar0, ar1);
            DOT16(wzv, hv, az0, az1);
            DOT16(wnv, hv, an0, an1);
        }

        float pr = xr0 + ar0 + ar1 + bhr;
        float pz = xz0 + az0 + az1 + bhz;
        float r = __builtin_amdgcn_rcpf(1.f + __expf(-pr));
        float z = __builtin_amdgcn_rcpf(1.f + __expf(-pz));
        float pn = xn0 + r * (an0 + an1 + bhn);
        // tanh(pn) = 1 - 2/(exp(2*pn)+1); exp overflow->inf->rcp 0 saturates correctly
        float th = 1.f - 2.f * __builtin_amdgcn_rcpf(__expf(2.f * pn) + 1.f);
        hreg = th + z * (hreg - th);

        xob[(size_t)t * ldx] = __float2bfloat16(hreg);
        xr0 = xr1; xz0 = xz1; xn0 = xn1;
        xr1 = nr;  xz1 = nz;  xn1 = nn;
    }
}

extern "C" void kernel_launch(void* const* d_in, const int* in_sizes, int n_in,
                              void* d_out, int out_size, void* d_ws, size_t ws_size,
                              hipStream_t stream) {
    const float* features = (const float*)d_in[0];
    const float* d1_w = (const float*)d_in[1];
    const float* d1_b = (const float*)d_in[2];
    const float* z_w  = (const float*)d_in[33];
    const float* z_b  = (const float*)d_in[34];
    const float* s1_w = (const float*)d_in[35];
    const float* s1_b = (const float*)d_in[36];
    const float* s2_w = (const float*)d_in[37];
    const float* s2_b = (const float*)d_in[38];

    char* ws = (char*)d_ws;
    __hip_bfloat16* xbf  = (__hip_bfloat16*)ws;                    // [ROWS][544] bf16
    float*          xp   = (float*)(ws + 71303168ull);             // [ROWS][192] f32
    __hip_bfloat16* fbf  = (__hip_bfloat16*)(ws + 121634816ull);   // [ROWS][64] bf16
    __hip_bfloat16* s1b  = (__hip_bfloat16*)(ws + 130023424ull);   // [ROWS][128] bf16
    __hip_bfloat16* wbuf = (__hip_bfloat16*)(ws + 146800640ull);   // weights bf16

    float* zout = (float*)d_out;                 // [ROWS][80]
    float* sout = zout + (size_t)ROWS * 80;      // [ROWS][24]

    const int gru_in[5] = {64, 160, 256, 352, 448};
    const int dil[5]    = {1, 2, 2, 2, 2};

    WTab tab;
    long long off = 0;
    auto add = [&](int i, const float* src, int N, int Npad, int K, int Kpad, int dcv) {
        tab.e[i].src = src; tab.e[i].N = N; tab.e[i].Npad = Npad;
        tab.e[i].K = K; tab.e[i].Kpad = Kpad; tab.e[i].dc = dcv; tab.e[i].off = off;
        off += (long long)Npad * Kpad;
    };
    add(0, d1_w, 64, 64, 40, 64, 0);
    for (int n = 0; n < 5; ++n)
        add(1 + n, (const float*)d_in[3 + n * 4], 192, 192, gru_in[n], gru_in[n], 0);
    for (int n = 0; n < 5; ++n) {
        int dcv = gru_in[n] + 64;
        add(6 + n, (const float*)d_in[23 + n * 2], 32, 64, 2 * dcv, 2 * dcv, dcv);
    }
    add(11, z_w, 80, 128, 544, 544, 0);
    add(12, s1_w, 128, 128, 544, 544, 0);
    add(13, s2_w, 24, 64, 128, 128, 0);

    prep_weights<<<dim3(14, 16), 256, 0, stream>>>(tab, wbuf);
    prep_features<<<2048, 256, 0, stream>>>(features, fbf);

    // d1: xbf[:,0:64] = tanh(fbf @ d1_w^T + b)
    mm_bf16<<<dim3(512, 1), 256, 0, stream>>>(
        fbf, 64, wbuf + tab.e[0].off, 64, d1_b, xbf, XW, 0, 64, 64, 0, 0, 1, 1);

    for (int n = 0; n < 5; ++n) {
        const float* whh = (const float*)d_in[3 + n * 4 + 1];
        const float* bih = (const float*)d_in[3 + n * 4 + 2];
        const float* bhh = (const float*)d_in[3 + n * 4 + 3];
        const float* cb  = (const float*)d_in[23 + n * 2 + 1];
        const int din = gru_in[n];
        const int dcv = din + 64;

        // xp = xbf[:,0:din] @ wih^T + bih   (fp32 out)
        mm_bf16<<<dim3(512, 3), 256, 0, stream>>>(
            xbf, XW, wbuf + tab.e[1 + n].off, din, bih, xp, 192, 0, 192, din, 0, 0, 0, 0);

        // sequential GRU scan -> xbf[:, din:din+64]
        gru_scan_kernel<<<dim3(128), dim3(64), 0, stream>>>(xp, whh, bhh, xbf, XW, din);

        // conv (both taps, one GEMM over K=2*dcv) -> xbf[:, dcv:dcv+32]
        mm_bf16<<<dim3(512, 1), 256, 0, stream>>>(
            xbf, XW, wbuf + tab.e[6 + n].off, 2 * dcv, cb, xbf, XW, dcv, 32, 2 * dcv,
            dcv, dil[n], 1, 1);
    }

    // z = xbf @ z_w^T + z_b (fp32 out)
    mm_bf16<<<dim3(512, 2), 256, 0, stream>>>(
        xbf, XW, wbuf + tab.e[11].off, 544, z_b, zout, 80, 0, 80, 544, 0, 0, 0, 0);
    // s1 = tanh(xbf @ s1_w^T + s1_b) (bf16)
    mm_bf16<<<dim3(512, 2), 256, 0, stream>>>(
        xbf, XW, wbuf + tab.e[12].off, 544, s1_b, s1b, 128, 0, 128, 544, 0, 0, 1, 1);
    // states = tanh(s1b @ s2_w^T + s2_b) (fp32 out)
    mm_bf16<<<dim3(512, 1), 256, 0, stream>>>(
        s1b, 128, wbuf + tab.e[13].off, 128, s2_b, sout, 24, 0, 24, 128, 0, 0, 1, 0);
}

// Round 11
// 1282.851 us; speedup vs baseline: 2.5412x; 1.0393x over previous
//
#include <hip/hip_runtime.h>
#include <hip/hip_bf16.h>
#include <cstddef>

#define T_STEPS 512
#define ROWS    65536      // B*T = 128*512
#define XW      544        // full feature width

typedef __attribute__((ext_vector_type(8))) short bf16x8;
typedef __attribute__((ext_vector_type(4))) float f32x4;
typedef _Float16 half_t;
typedef __attribute__((ext_vector_type(2))) _Float16 half2_t;

__device__ __forceinline__ float fast_tanh(float x) {
    x = fminf(fmaxf(x, -15.f), 15.f);
    float e = __expf(2.f * x);
    return (e - 1.f) / (e + 1.f);
}

// ---------------------------------------------------------------------------
// Weight prep: fp32 -> bf16, layout [Npad][Kpad] row-major, zero padded.
// mode dc>0: conv weight src [N][dc][2] -> dst[n][k] = k<dc ? w[n][k][0] : w[n][k-dc][1]
// ---------------------------------------------------------------------------
struct WDesc { const float* src; int N; int Npad; int K; int Kpad; int dc; long long off; };
struct WTab  { WDesc e[14]; };

__global__ __launch_bounds__(256) void prep_weights(WTab tab, __hip_bfloat16* __restrict__ dst) {
    WDesc d = tab.e[blockIdx.x];
    const int total = d.Npad * d.Kpad;
    for (int idx = blockIdx.y * blockDim.x + threadIdx.x; idx < total;
         idx += gridDim.y * blockDim.x) {
        int n = idx / d.Kpad;
        int k = idx - n * d.Kpad;
        float v = 0.f;
        if (n < d.N && k < d.K) {
            if (d.dc > 0)
                v = (k < d.dc) ? d.src[(n * d.dc + k) * 2]
                               : d.src[(n * d.dc + (k - d.dc)) * 2 + 1];
            else
                v = d.src[(size_t)n * d.K + k];
        }
        dst[d.off + idx] = __float2bfloat16(v);
    }
}

// features [ROWS][40] fp32 -> fbf [ROWS][64] bf16 (zero padded)
__global__ __launch_bounds__(256) void prep_features(const float* __restrict__ f,
                                                     __hip_bfloat16* __restrict__ o) {
    for (int idx = blockIdx.x * blockDim.x + threadIdx.x; idx < ROWS * 64;
         idx += gridDim.x * blockDim.x) {
        int r = idx >> 6, c = idx & 63;
        o[idx] = __float2bfloat16(c < 40 ? f[(size_t)r * 40 + c] : 0.f);
    }
}

// ---------------------------------------------------------------------------
// bf16 MFMA GEMM: C[row, ccol+n] = act( sum_k A[grow(row), k] * W[n][k] + bias[n] )
//  - tile 128x64, BK=32, 256 threads (4 waves; wave w: rows w*32..w*32+31, all 64 cols)
//  - A,W staged via global_load_lds(16B) with pre-swizzled source (granule XOR (row>>1)&3)
//  - dc>0: conv mode, K=2*dc; k<dc reads past row (t-gdil clamped), else current row
// ---------------------------------------------------------------------------
__global__ __launch_bounds__(256) void mm_bf16(
    const __hip_bfloat16* __restrict__ A, int lda,
    const __hip_bfloat16* __restrict__ W, int ldw,
    const float* __restrict__ bias,
    void* __restrict__ Cout, int ldc, int ccol, int N, int K,
    int dc, int gdil, int act, int outbf)
{
    __shared__ __align__(16) unsigned short As[128 * 32];
    __shared__ __align__(16) unsigned short Ws[64 * 32];

    const int tid  = threadIdx.x;
    const int w    = tid >> 6;
    const int lane = tid & 63;
    const int m0   = blockIdx.x * 128;
    const int n0   = blockIdx.y * 64;

    f32x4 acc[2][4];
#pragma unroll
    for (int m = 0; m < 2; ++m)
#pragma unroll
        for (int n = 0; n < 4; ++n) acc[m][n] = (f32x4){0.f, 0.f, 0.f, 0.f};

    const int ksteps = K >> 5;
    for (int kc = 0; kc < ksteps; ++kc) {
        const int k0 = kc << 5;
#pragma unroll
        for (int it = 0; it < 2; ++it) {
            int s  = it * 256 + w * 64 + lane;
            int rl = s >> 2, g = s & 3;
            int gq = g ^ ((rl >> 1) & 3);
            int grow = m0 + rl;
            int gcol = k0 + gq * 8;
            if (dc > 0) {
                if (k0 < dc) {
                    int t = grow & (T_STEPS - 1);
                    int tp = t - gdil; if (tp < 0) tp = 0;
                    grow = (grow & ~(T_STEPS - 1)) | tp;
                } else {
                    gcol -= dc;
                }
            }
            __builtin_amdgcn_global_load_lds(
                (const __attribute__((address_space(1))) void*)(A + (size_t)grow * lda + gcol),
                (__attribute__((address_space(3))) void*)(As + (size_t)(it * 256 + w * 64) * 8),
                16, 0, 0);
        }
        {
            int s  = w * 64 + lane;
            int rl = s >> 2, g = s & 3;
            int gq = g ^ ((rl >> 1) & 3);
            __builtin_amdgcn_global_load_lds(
                (const __attribute__((address_space(1))) void*)(W + (size_t)(n0 + rl) * ldw + k0 + gq * 8),
                (__attribute__((address_space(3))) void*)(Ws + (size_t)(w * 64) * 8),
                16, 0, 0);
        }
        __syncthreads();

        const int q = lane >> 4, li = lane & 15;
        bf16x8 af[2], wf[4];
#pragma unroll
        for (int m = 0; m < 2; ++m) {
            int r = w * 32 + m * 16 + li;
            af[m] = *(const bf16x8*)(As + (size_t)(r * 4 + (q ^ ((r >> 1) & 3))) * 8);
        }
#pragma unroll
        for (int n = 0; n < 4; ++n) {
            int r = n * 16 + li;
            wf[n] = *(const bf16x8*)(Ws + (size_t)(r * 4 + (q ^ ((r >> 1) & 3))) * 8);
        }
#pragma unroll
        for (int m = 0; m < 2; ++m)
#pragma unroll
            for (int n = 0; n < 4; ++n)
                acc[m][n] = __builtin_amdgcn_mfma_f32_16x16x32_bf16(af[m], wf[n], acc[m][n], 0, 0, 0);
        __syncthreads();
    }

    const int q = lane >> 4, li = lane & 15;
#pragma unroll
    for (int m = 0; m < 2; ++m) {
#pragma unroll
        for (int n = 0; n < 4; ++n) {
            int col = n0 + n * 16 + li;
            if (col < N) {
                float bv = bias ? bias[col] : 0.f;
#pragma unroll
                for (int j = 0; j < 4; ++j) {
                    int row = m0 + w * 32 + m * 16 + q * 4 + j;
                    float v = acc[m][n][j] + bv;
                    if (act) v = fast_tanh(v);
                    if (outbf)
                        ((__hip_bfloat16*)Cout)[(size_t)row * ldc + ccol + col] = __float2bfloat16(v);
                    else
                        ((float*)Cout)[(size_t)row * ldc + ccol + col] = v;
                }
            }
        }
    }
}

// ---------------------------------------------------------------------------
// GRU scan, one wave per batch, ZERO barriers.
// R10 showed LDS weight file == scratch spill (~190us): storage wasn't the
// bottleneck -- the SCHEDULE was (batched ds_reads with per-batch lgkmcnt
// RAW latency on the critical chain). This version hand-pipelines:
//  - all 8 h broadcast reads issued as NAMED regs right after the h publish
//  - weight reads (loop-invariant, h-independent) rolled through a named
//    2-chunk prefetch window so LDS pipe overlaps the fdot2 stream
// ---------------------------------------------------------------------------
__global__ __launch_bounds__(64, 1) void gru_scan_kernel(
    const float* __restrict__ xp,    // [B*T, 192] = x@wih^T + bih (fp32)
    const float* __restrict__ whh,   // [192, 64]
    const float* __restrict__ bhh,   // [192]
    __hip_bfloat16* __restrict__ xout, int ldx, int ccol)
{
    __shared__ __align__(16) uint4 wlds[8 * 192];    // [chunk][row] 16B each = 24 KB
    __shared__ __align__(16) unsigned int hs2[32];   // h as packed f16 pairs

    const int b = blockIdx.x;
    const int l = threadIdx.x;

#define PKF2(a, c) __builtin_bit_cast(unsigned int, __builtin_amdgcn_cvt_pkrtz(a, c))

    // pack own 3 rows of whh (f32 -> f16 pairs) into LDS
#pragma unroll
    for (int j = 0; j < 3; ++j) {
        const int row = j * 64 + l;
        const float4* src = (const float4*)(whh + (size_t)row * 64);
#pragma unroll
        for (int c = 0; c < 8; ++c) {
            float4 a = src[2 * c], d = src[2 * c + 1];
            wlds[c * 192 + row] = (uint4){ PKF2(a.x, a.y), PKF2(a.z, a.w),
                                           PKF2(d.x, d.y), PKF2(d.z, d.w) };
        }
    }

    const float bhr = bhh[l], bhz = bhh[64 + l], bhn = bhh[128 + l];

    const float* xpb = xp + (size_t)b * T_STEPS * 192;
    __hip_bfloat16* xob = xout + (size_t)b * T_STEPS * ldx + ccol + l;

    float hreg = 0.f;
    float xr0 = xpb[l],       xz0 = xpb[64 + l],  xn0 = xpb[128 + l];
    float xr1 = xpb[192 + l], xz1 = xpb[256 + l], xn1 = xpb[320 + l];

#if __has_builtin(__builtin_amdgcn_fdot2)
#define D2(wu, hu, acc) acc = __builtin_amdgcn_fdot2(                           \
        __builtin_bit_cast(half2_t, (unsigned int)(wu)),                        \
        __builtin_bit_cast(half2_t, (unsigned int)(hu)), acc, false)
#else
#define D2(wu, hu, acc) { half2_t w_ = __builtin_bit_cast(half2_t, (unsigned int)(wu)); \
        half2_t h_ = __builtin_bit_cast(half2_t, (unsigned int)(hu));           \
        acc += (float)w_.x * (float)h_.x + (float)w_.y * (float)h_.y; }
#endif
#define DOT16(wv, hv, a0, a1)                                                   \
    D2(wv.x, hv.x, a0); D2(wv.y, hv.y, a1); D2(wv.z, hv.z, a0); D2(wv.w, hv.w, a1);

    const uint4* wR = wlds + l;          // + c*192
    const uint4* wZ = wlds + 64 + l;
    const uint4* wN = wlds + 128 + l;
    const uint4* hp = (const uint4*)hs2;

    for (int t = 0; t < T_STEPS; ++t) {
        // weight prefetch window: chunks 0,1 (loop-invariant, no h dependence)
        uint4 wr0 = wR[0 * 192], wz0 = wZ[0 * 192], wn0 = wN[0 * 192];
        uint4 wr1 = wR[1 * 192], wz1 = wZ[1 * 192], wn1 = wN[1 * 192];

        // publish own h, then issue ALL broadcast h reads (named, in-order LDS)
        ((half_t*)hs2)[l] = (half_t)hreg;
        uint4 h0 = hp[0], h1 = hp[1], h2 = hp[2], h3 = hp[3];
        uint4 h4v = hp[4], h5 = hp[5], h6 = hp[6], h7 = hp[7];

        // xp prefetch for step t+2 (global; off critical path)
        float nr = 0.f, nz = 0.f, nn = 0.f;
        if (t + 2 < T_STEPS) {
            const float* p = xpb + (size_t)(t + 2) * 192;
            nr = p[l]; nz = p[64 + l]; nn = p[128 + l];
        }

        float ar0 = 0.f, ar1 = 0.f, az0 = 0.f, az1 = 0.f, an0 = 0.f, an1 = 0.f;

        uint4 wr2 = wR[2 * 192], wz2 = wZ[2 * 192], wn2 = wN[2 * 192];
        DOT16(wr0, h0, ar0, ar1); DOT16(wz0, h0, az0, az1); DOT16(wn0, h0, an0, an1);
        uint4 wr3 = wR[3 * 192], wz3 = wZ[3 * 192], wn3 = wN[3 * 192];
        DOT16(wr1, h1, ar0, ar1); DOT16(wz1, h1, az0, az1); DOT16(wn1, h1, an0, an1);
        uint4 wr4 = wR[4 * 192], wz4 = wZ[4 * 192], wn4 = wN[4 * 192];
        DOT16(wr2, h2, ar0, ar1); DOT16(wz2, h2, az0, az1); DOT16(wn2, h2, an0, an1);
        uint4 wr5 = wR[5 * 192], wz5 = wZ[5 * 192], wn5 = wN[5 * 192];
        DOT16(wr3, h3, ar0, ar1); DOT16(wz3, h3, az0, az1); DOT16(wn3, h3, an0, an1);
        uint4 wr6 = wR[6 * 192], wz6 = wZ[6 * 192], wn6 = wN[6 * 192];
        DOT16(wr4, h4v, ar0, ar1); DOT16(wz4, h4v, az0, az1); DOT16(wn4, h4v, an0, an1);
        uint4 wr7 = wR[7 * 192], wz7 = wZ[7 * 192], wn7 = wN[7 * 192];
        DOT16(wr5, h5, ar0, ar1); DOT16(wz5, h5, az0, az1); DOT16(wn5, h5, an0, an1);
        DOT16(wr6, h6, ar0, ar1); DOT16(wz6, h6, az0, az1); DOT16(wn6, h6, an0, an1);
        DOT16(wr7, h7, ar0, ar1); DOT16(wz7, h7, az0, az1); DOT16(wn7, h7, an0, an1);

        float pr = xr0 + ar0 + ar1 + bhr;
        float pz = xz0 + az0 + az1 + bhz;
        float r = __builtin_amdgcn_rcpf(1.f + __expf(-pr));
        float z = __builtin_amdgcn_rcpf(1.f + __expf(-pz));
        float pn = xn0 + r * (an0 + an1 + bhn);
        // tanh(pn) = 1 - 2/(exp(2*pn)+1); exp overflow->inf->rcp 0 saturates correctly
        float th = 1.f - 2.f * __builtin_amdgcn_rcpf(__expf(2.f * pn) + 1.f);
        hreg = th + z * (hreg - th);

        xob[(size_t)t * ldx] = __float2bfloat16(hreg);
        xr0 = xr1; xz0 = xz1; xn0 = xn1;
        xr1 = nr;  xz1 = nz;  xn1 = nn;
    }
}

extern "C" void kernel_launch(void* const* d_in, const int* in_sizes, int n_in,
                              void* d_out, int out_size, void* d_ws, size_t ws_size,
                              hipStream_t stream) {
    const float* features = (const float*)d_in[0];
    const float* d1_w = (const float*)d_in[1];
    const float* d1_b = (const float*)d_in[2];
    const float* z_w  = (const float*)d_in[33];
    const float* z_b  = (const float*)d_in[34];
    const float* s1_w = (const float*)d_in[35];
    const float* s1_b = (const float*)d_in[36];
    const float* s2_w = (const float*)d_in[37];
    const float* s2_b = (const float*)d_in[38];

    char* ws = (char*)d_ws;
    __hip_bfloat16* xbf  = (__hip_bfloat16*)ws;                    // [ROWS][544] bf16
    float*          xp   = (float*)(ws + 71303168ull);             // [ROWS][192] f32
    __hip_bfloat16* fbf  = (__hip_bfloat16*)(ws + 121634816ull);   // [ROWS][64] bf16
    __hip_bfloat16* s1b  = (__hip_bfloat16*)(ws + 130023424ull);   // [ROWS][128] bf16
    __hip_bfloat16* wbuf = (__hip_bfloat16*)(ws + 146800640ull);   // weights bf16

    float* zout = (float*)d_out;                 // [ROWS][80]
    float* sout = zout + (size_t)ROWS * 80;      // [ROWS][24]

    const int gru_in[5] = {64, 160, 256, 352, 448};
    const int dil[5]    = {1, 2, 2, 2, 2};

    WTab tab;
    long long off = 0;
    auto add = [&](int i, const float* src, int N, int Npad, int K, int Kpad, int dcv) {
        tab.e[i].src = src; tab.e[i].N = N; tab.e[i].Npad = Npad;
        tab.e[i].K = K; tab.e[i].Kpad = Kpad; tab.e[i].dc = dcv; tab.e[i].off = off;
        off += (long long)Npad * Kpad;
    };
    add(0, d1_w, 64, 64, 40, 64, 0);
    for (int n = 0; n < 5; ++n)
        add(1 + n, (const float*)d_in[3 + n * 4], 192, 192, gru_in[n], gru_in[n], 0);
    for (int n = 0; n < 5; ++n) {
        int dcv = gru_in[n] + 64;
        add(6 + n, (const float*)d_in[23 + n * 2], 32, 64, 2 * dcv, 2 * dcv, dcv);
    }
    add(11, z_w, 80, 128, 544, 544, 0);
    add(12, s1_w, 128, 128, 544, 544, 0);
    add(13, s2_w, 24, 64, 128, 128, 0);

    prep_weights<<<dim3(14, 16), 256, 0, stream>>>(tab, wbuf);
    prep_features<<<2048, 256, 0, stream>>>(features, fbf);

    // d1: xbf[:,0:64] = tanh(fbf @ d1_w^T + b)
    mm_bf16<<<dim3(512, 1), 256, 0, stream>>>(
        fbf, 64, wbuf + tab.e[0].off, 64, d1_b, xbf, XW, 0, 64, 64, 0, 0, 1, 1);

    for (int n = 0; n < 5; ++n) {
        const float* whh = (const float*)d_in[3 + n * 4 + 1];
        const float* bih = (const float*)d_in[3 + n * 4 + 2];
        const float* bhh = (const float*)d_in[3 + n * 4 + 3];
        const float* cb  = (const float*)d_in[23 + n * 2 + 1];
        const int din = gru_in[n];
        const int dcv = din + 64;

        // xp = xbf[:,0:din] @ wih^T + bih   (fp32 out)
        mm_bf16<<<dim3(512, 3), 256, 0, stream>>>(
            xbf, XW, wbuf + tab.e[1 + n].off, din, bih, xp, 192, 0, 192, din, 0, 0, 0, 0);

        // sequential GRU scan -> xbf[:, din:din+64]
        gru_scan_kernel<<<dim3(128), dim3(64), 0, stream>>>(xp, whh, bhh, xbf, XW, din);

        // conv (both taps, one GEMM over K=2*dcv) -> xbf[:, dcv:dcv+32]
        mm_bf16<<<dim3(512, 1), 256, 0, stream>>>(
            xbf, XW, wbuf + tab.e[6 + n].off, 2 * dcv, cb, xbf, XW, dcv, 32, 2 * dcv,
            dcv, dil[n], 1, 1);
    }

    // z = xbf @ z_w^T + z_b (fp32 out)
    mm_bf16<<<dim3(512, 2), 256, 0, stream>>>(
        xbf, XW, wbuf + tab.e[11].off, 544, z_b, zout, 80, 0, 80, 544, 0, 0, 0, 0);
    // s1 = tanh(xbf @ s1_w^T + s1_b) (bf16)
    mm_bf16<<<dim3(512, 2), 256, 0, stream>>>(
        xbf, XW, wbuf + tab.e[12].off, 544, s1_b, s1b, 128, 0, 128, 544, 0, 0, 1, 1);
    // states = tanh(s1b @ s2_w^T + s2_b) (fp32 out)
    mm_bf16<<<dim3(512, 1), 256, 0, stream>>>(
        s1b, 128, wbuf + tab.e[13].off, 128, s2_b, sout, 24, 0, 24, 128, 0, 0, 1, 0);
}